// Round 4
// baseline (312.361 us; speedup 1.0000x reference)
//
#include <hip/hip_runtime.h>
#include <hip/hip_bf16.h>

#define NN 100000
#define NE 1600000
#define NBUCK 98  // ceil(NN / 1024)

typedef __attribute__((ext_vector_type(8))) short short8;
typedef __attribute__((ext_vector_type(4))) float f32x4;

static __device__ __forceinline__ unsigned short f2bf(float f) {
    unsigned u = __float_as_uint(f);
    unsigned r = (u + 0x7fffu + ((u >> 16) & 1u)) >> 16;
    return (unsigned short)r;
}
static __device__ __forceinline__ float bf2f(unsigned short s) {
    return __uint_as_float(((unsigned)s) << 16);
}

// ---------- bucketed CSR build ----------
__global__ __launch_bounds__(256) void k_bcount(const int* __restrict__ ei,
                                                int* __restrict__ bcnt) {
    __shared__ int h[NBUCK];
    int tid = threadIdx.x;
    for (int i = tid; i < NBUCK; i += 256) h[i] = 0;
    __syncthreads();
    for (int e = blockIdx.x * 256 + tid; e < NE; e += gridDim.x * 256)
        atomicAdd(&h[ei[NE + e] >> 10], 1);
    __syncthreads();
    for (int i = tid; i < NBUCK; i += 256) atomicAdd(&bcnt[i], h[i]);
}

__global__ __launch_bounds__(128) void k_bbase(const int* __restrict__ bcnt,
                                               int* __restrict__ bbase,
                                               int* __restrict__ bcur) {
    __shared__ int s[128];
    int tid = threadIdx.x;
    int v = (tid < NBUCK) ? bcnt[tid] : 0;
    s[tid] = v;
    __syncthreads();
    #pragma unroll
    for (int off = 1; off < 128; off <<= 1) {
        int t = (tid >= off) ? s[tid - off] : 0;
        __syncthreads();
        s[tid] += t;
        __syncthreads();
    }
    if (tid < NBUCK) {
        int ex = s[tid] - v;
        bbase[tid] = ex;
        bcur[tid] = ex;
    }
}

#define CHUNK 8192
__global__ __launch_bounds__(256) void k_partition(const int* __restrict__ ei,
                                                   int* __restrict__ bcur,
                                                   unsigned* __restrict__ ebuf) {
    __shared__ int lh[NBUCK];
    __shared__ int lbase[NBUCK];
    int tid = threadIdx.x;
    int e0 = blockIdx.x * CHUNK;
    for (int i = tid; i < NBUCK; i += 256) lh[i] = 0;
    __syncthreads();
    #pragma unroll 4
    for (int k = 0; k < CHUNK; k += 256) {
        int e = e0 + k + tid;
        if (e < NE) atomicAdd(&lh[ei[NE + e] >> 10], 1);
    }
    __syncthreads();
    if (tid < NBUCK) {
        int c = lh[tid];
        lbase[tid] = c ? atomicAdd(&bcur[tid], c) : 0;
        lh[tid] = 0;  // becomes local rank counter
    }
    __syncthreads();
    #pragma unroll 4
    for (int k = 0; k < CHUNK; k += 256) {
        int e = e0 + k + tid;
        if (e < NE) {
            int d = ei[NE + e];
            int s = ei[e];
            int b = d >> 10;
            int r = atomicAdd(&lh[b], 1);
            ebuf[lbase[b] + r] = ((unsigned)s << 10) | (unsigned)(d & 1023);
        }
    }
}

__global__ __launch_bounds__(1024) void k_build(const int* __restrict__ bbase,
                                                const int* __restrict__ bcnt,
                                                const unsigned* __restrict__ ebuf,
                                                int* __restrict__ row_ptr,
                                                float* __restrict__ dinv,
                                                int* __restrict__ esrc) {
    __shared__ int cnt[1024];
    __shared__ int s[1024];
    int tid = threadIdx.x;
    int base = bbase[blockIdx.x];
    int nedge = bcnt[blockIdx.x];
    cnt[tid] = 0;
    __syncthreads();
    for (int j = tid; j < nedge; j += 1024)
        atomicAdd(&cnt[ebuf[base + j] & 1023u], 1);
    __syncthreads();
    int v = cnt[tid];
    s[tid] = v;
    __syncthreads();
    #pragma unroll
    for (int off = 1; off < 1024; off <<= 1) {
        int t = (tid >= off) ? s[tid - off] : 0;
        __syncthreads();
        s[tid] += t;
        __syncthreads();
    }
    int ex = s[tid] - v;
    int node = blockIdx.x * 1024 + tid;
    if (node < NN) {
        row_ptr[node] = base + ex;
        dinv[node] = rsqrtf((float)(v + 1));  // +1 self-loop
    }
    if (blockIdx.x == 0 && tid == 0) row_ptr[NN] = NE;
    cnt[tid] = base + ex;  // becomes cursor
    __syncthreads();
    for (int j = tid; j < nedge; j += 1024) {
        unsigned p = ebuf[base + j];
        int pos = atomicAdd(&cnt[p & 1023u], 1);
        esrc[pos] = (int)(p >> 10);
    }
}

// ---------- h = in @ W  [N x K] @ [K x 64] -> bf16; in fp32 or bf16 ----------
template <int K, bool BF16IN>
__global__ __launch_bounds__(256) void k_mm(const void* __restrict__ in_,
                                            const float* __restrict__ W,
                                            unsigned short* __restrict__ hout) {
    constexpr int KP = K + 8;  // 2-way bank alias only (free)
    __shared__ unsigned short Wt[64 * KP];
    int tid = threadIdx.x;
    for (int idx = tid; idx < K * 64; idx += 256) {
        int k = idx >> 6, n = idx & 63;
        Wt[n * KP + k] = f2bf(W[idx]);
    }
    __syncthreads();

    int wave = tid >> 6, lane = tid & 63;
    int m = lane & 15, q = lane >> 4;
    int n0 = blockIdx.x * 64 + wave * 16;

    f32x4 acc[4] = {{0.f,0.f,0.f,0.f},{0.f,0.f,0.f,0.f},{0.f,0.f,0.f,0.f},{0.f,0.f,0.f,0.f}};
    int row = n0 + m;
    int rowc = row < NN ? row : NN - 1;

    #pragma unroll
    for (int kk = 0; kk < K / 32; ++kk) {
        short8 afrag;
        if (BF16IN) {
            const unsigned short* xr = (const unsigned short*)in_ + (long)rowc * K;
            afrag = *(const short8*)(xr + kk * 32 + q * 8);
        } else {
            const float* xr = (const float*)in_ + (long)rowc * K;
            const float4* p = (const float4*)(xr + kk * 32 + q * 8);
            float4 v0 = p[0], v1 = p[1];
            float xv[8] = {v0.x, v0.y, v0.z, v0.w, v1.x, v1.y, v1.z, v1.w};
            #pragma unroll
            for (int i2 = 0; i2 < 8; ++i2) afrag[i2] = (short)f2bf(xv[i2]);
        }
        #pragma unroll
        for (int nt = 0; nt < 4; ++nt) {
            const short8* bp = (const short8*)&Wt[(nt * 16 + m) * KP + kk * 32 + q * 8];
            acc[nt] = __builtin_amdgcn_mfma_f32_16x16x32_bf16(afrag, *bp, acc[nt], 0, 0, 0);
        }
    }

    // D layout: col=lane&15, row=(lane>>4)*4+reg  [m89-verified]
    #pragma unroll
    for (int reg = 0; reg < 4; ++reg) {
        int node = n0 + q * 4 + reg;
        if (node < NN) {
            #pragma unroll
            for (int nt = 0; nt < 4; ++nt)
                hout[(long)node * 64 + nt * 16 + m] = f2bf(acc[nt][reg]);
        }
    }
}

// ---------- per-node aggregation: half-wave per node ----------
// stage 32 indices coalesced -> batch dinv gathers -> shfl-broadcast ->
// independent h-row gathers (unroll 8). PReLU fused. OUT_BF16: packed bf16x2.
template <bool OUT_BF16>
__global__ __launch_bounds__(256) void k_agg(const int* __restrict__ row_ptr,
                                             const int* __restrict__ esrc,
                                             const unsigned short* __restrict__ h,
                                             const float* __restrict__ dinv,
                                             const float* __restrict__ bias,
                                             const float* __restrict__ alpha,
                                             void* __restrict__ out_) {
    int node = blockIdx.x * 8 + (threadIdx.x >> 5);
    int l = threadIdx.x & 31;
    if (node >= NN) return;
    int start = row_ptr[node], end = row_ptr[node + 1];
    float dn = dinv[node];

    // self-loop: norm = dinv[node]^2
    unsigned hv = *(const unsigned*)(h + (long)node * 64 + l * 2);
    float d2 = dn * dn;
    float a0 = bf2f((unsigned short)(hv & 0xffffu)) * d2;
    float a1 = bf2f((unsigned short)(hv >> 16)) * d2;

    for (int base = start; base < end; base += 32) {
        int cnt = end - base;
        if (cnt > 32) cnt = 32;
        // stage: lane l owns edge base+l
        int myidx = 0;
        float mynorm = 0.f;
        if (l < cnt) {
            myidx = esrc[base + l];
            mynorm = dinv[myidx] * dn;
        }
        for (int c = 0; c < cnt; c += 8) {
            #pragma unroll
            for (int j = 0; j < 8; ++j) {
                if (c + j < cnt) {
                    int s = __shfl(myidx, c + j, 32);
                    float nm = __shfl(mynorm, c + j, 32);
                    unsigned hw = *(const unsigned*)(h + (long)s * 64 + l * 2);
                    a0 += bf2f((unsigned short)(hw & 0xffffu)) * nm;
                    a1 += bf2f((unsigned short)(hw >> 16)) * nm;
                }
            }
        }
    }

    a0 += bias[l * 2];
    a1 += bias[l * 2 + 1];
    float al0 = alpha[l * 2], al1 = alpha[l * 2 + 1];
    a0 = a0 >= 0.f ? a0 : al0 * a0;
    a1 = a1 >= 0.f ? a1 : al1 * a1;

    if (OUT_BF16) {
        unsigned pk = (unsigned)f2bf(a0) | ((unsigned)f2bf(a1) << 16);
        ((unsigned*)out_)[(long)node * 32 + l] = pk;
    } else {
        float2* op = (float2*)((float*)out_ + (long)node * 64 + l * 2);
        *op = make_float2(a0, a1);
    }
}

extern "C" void kernel_launch(void* const* d_in, const int* in_sizes, int n_in,
                              void* d_out, int out_size, void* d_ws, size_t ws_size,
                              hipStream_t stream) {
    const float* x     = (const float*)d_in[0];
    const int*   ei    = (const int*)d_in[1];
    const float* W1    = (const float*)d_in[2];
    const float* b1    = (const float*)d_in[3];
    const float* W2    = (const float*)d_in[4];
    const float* b2    = (const float*)d_in[5];
    const float* alpha = (const float*)d_in[6];
    float* out = (float*)d_out;

    char* ws = (char*)d_ws;
    float* dinv          = (float*)(ws);                     //        0: 400,384
    int*   row_ptr       = (int*)(ws + 400384);              //   400384: 400,384
    int*   bcnt          = (int*)(ws + 800768);              //   800768: 512
    int*   bbase         = (int*)(ws + 801280);              //   801280: 512
    int*   bcur          = (int*)(ws + 801792);              //   801792: 512
    int*   esrc          = (int*)(ws + 802304);              //   802304: 6,400,000
    unsigned short* hbf  = (unsigned short*)(ws + 7202304);  //  7202304: 12,800,000
    unsigned* ebuf       = (unsigned*)(ws + 20002304);       // 20002304: 6,400,000 (dead after k_build)
    unsigned short* aggbf= (unsigned short*)(ws + 20002304); // alias ebuf: 12,800,000
    // total: 32,802,304 B

    hipMemsetAsync(bcnt, 0, NBUCK * sizeof(int), stream);
    k_bcount<<<256, 256, 0, stream>>>(ei, bcnt);
    k_bbase<<<1, 128, 0, stream>>>(bcnt, bbase, bcur);
    k_partition<<<(NE + CHUNK - 1) / CHUNK, 256, 0, stream>>>(ei, bcur, ebuf);
    k_build<<<NBUCK, 1024, 0, stream>>>(bbase, bcnt, ebuf, row_ptr, dinv, esrc);

    // layer 1: h1 = x@W1 (bf16) ; agg1 = prelu(scatter+self+b1) -> bf16
    k_mm<128, false><<<(NN + 63) / 64, 256, 0, stream>>>(x, W1, hbf);
    k_agg<true><<<(NN + 7) / 8, 256, 0, stream>>>(row_ptr, esrc, hbf, dinv, b1, alpha, aggbf);
    // layer 2: h2 = agg1@W2 (bf16 in) ; out = prelu(...) fp32
    k_mm<64, true><<<(NN + 63) / 64, 256, 0, stream>>>(aggbf, W2, hbf);
    k_agg<false><<<(NN + 7) / 8, 256, 0, stream>>>(row_ptr, esrc, hbf, dinv, b2, alpha, out);
}

// Round 5
// 266.802 us; speedup vs baseline: 1.1708x; 1.1708x over previous
//
#include <hip/hip_runtime.h>
#include <hip/hip_bf16.h>

#define NN 100000
#define NE 1600000
#define NBUCK 98  // ceil(NN / 1024)

typedef __attribute__((ext_vector_type(8))) short short8;
typedef __attribute__((ext_vector_type(4))) float f32x4;

static __device__ __forceinline__ unsigned short f2bf(float f) {
    unsigned u = __float_as_uint(f);
    unsigned r = (u + 0x7fffu + ((u >> 16) & 1u)) >> 16;
    return (unsigned short)r;
}
static __device__ __forceinline__ float bf_lo(unsigned u) {
    return __uint_as_float(u << 16);
}
static __device__ __forceinline__ float bf_hi(unsigned u) {
    return __uint_as_float(u & 0xffff0000u);
}

// ---------- bucketed CSR build ----------
__global__ __launch_bounds__(256) void k_bcount(const int* __restrict__ ei,
                                                int* __restrict__ bcnt) {
    __shared__ int h[NBUCK];
    int tid = threadIdx.x;
    for (int i = tid; i < NBUCK; i += 256) h[i] = 0;
    __syncthreads();
    for (int e = blockIdx.x * 256 + tid; e < NE; e += gridDim.x * 256)
        atomicAdd(&h[ei[NE + e] >> 10], 1);
    __syncthreads();
    for (int i = tid; i < NBUCK; i += 256) atomicAdd(&bcnt[i], h[i]);
}

__global__ __launch_bounds__(128) void k_bbase(const int* __restrict__ bcnt,
                                               int* __restrict__ bbase,
                                               int* __restrict__ bcur) {
    __shared__ int s[128];
    int tid = threadIdx.x;
    int v = (tid < NBUCK) ? bcnt[tid] : 0;
    s[tid] = v;
    __syncthreads();
    #pragma unroll
    for (int off = 1; off < 128; off <<= 1) {
        int t = (tid >= off) ? s[tid - off] : 0;
        __syncthreads();
        s[tid] += t;
        __syncthreads();
    }
    if (tid < NBUCK) {
        int ex = s[tid] - v;
        bbase[tid] = ex;
        bcur[tid] = ex;
    }
}

#define CHUNK 8192
__global__ __launch_bounds__(256) void k_partition(const int* __restrict__ ei,
                                                   int* __restrict__ bcur,
                                                   unsigned* __restrict__ ebuf) {
    __shared__ int lh[NBUCK];
    __shared__ int lbase[NBUCK];
    int tid = threadIdx.x;
    int e0 = blockIdx.x * CHUNK;
    for (int i = tid; i < NBUCK; i += 256) lh[i] = 0;
    __syncthreads();
    #pragma unroll 4
    for (int k = 0; k < CHUNK; k += 256) {
        int e = e0 + k + tid;
        if (e < NE) atomicAdd(&lh[ei[NE + e] >> 10], 1);
    }
    __syncthreads();
    if (tid < NBUCK) {
        int c = lh[tid];
        lbase[tid] = c ? atomicAdd(&bcur[tid], c) : 0;
        lh[tid] = 0;  // becomes local rank counter
    }
    __syncthreads();
    #pragma unroll 4
    for (int k = 0; k < CHUNK; k += 256) {
        int e = e0 + k + tid;
        if (e < NE) {
            int d = ei[NE + e];
            int s = ei[e];
            int b = d >> 10;
            int r = atomicAdd(&lh[b], 1);
            ebuf[lbase[b] + r] = ((unsigned)s << 10) | (unsigned)(d & 1023);
        }
    }
}

__global__ __launch_bounds__(1024) void k_build(const int* __restrict__ bbase,
                                                const int* __restrict__ bcnt,
                                                const unsigned* __restrict__ ebuf,
                                                int* __restrict__ row_ptr,
                                                float* __restrict__ dinv,
                                                int* __restrict__ esrc) {
    __shared__ int cnt[1024];
    __shared__ int s[1024];
    int tid = threadIdx.x;
    int base = bbase[blockIdx.x];
    int nedge = bcnt[blockIdx.x];
    cnt[tid] = 0;
    __syncthreads();
    for (int j = tid; j < nedge; j += 1024)
        atomicAdd(&cnt[ebuf[base + j] & 1023u], 1);
    __syncthreads();
    int v = cnt[tid];
    s[tid] = v;
    __syncthreads();
    #pragma unroll
    for (int off = 1; off < 1024; off <<= 1) {
        int t = (tid >= off) ? s[tid - off] : 0;
        __syncthreads();
        s[tid] += t;
        __syncthreads();
    }
    int ex = s[tid] - v;
    int node = blockIdx.x * 1024 + tid;
    if (node < NN) {
        row_ptr[node] = base + ex;
        dinv[node] = rsqrtf((float)(v + 1));  // +1 self-loop
    }
    if (blockIdx.x == 0 && tid == 0) row_ptr[NN] = NE;
    cnt[tid] = base + ex;  // becomes cursor
    __syncthreads();
    for (int j = tid; j < nedge; j += 1024) {
        unsigned p = ebuf[base + j];
        int pos = atomicAdd(&cnt[p & 1023u], 1);
        esrc[pos] = (int)(p >> 10);
    }
}

// ---------- h = in @ W  [N x K] @ [K x 64] -> bf16; in fp32 or bf16 ----------
template <int K, bool BF16IN>
__global__ __launch_bounds__(256) void k_mm(const void* __restrict__ in_,
                                            const float* __restrict__ W,
                                            unsigned short* __restrict__ hout) {
    constexpr int KP = K + 8;  // 2-way bank alias only (free)
    __shared__ unsigned short Wt[64 * KP];
    int tid = threadIdx.x;
    for (int idx = tid; idx < K * 64; idx += 256) {
        int k = idx >> 6, n = idx & 63;
        Wt[n * KP + k] = f2bf(W[idx]);
    }
    __syncthreads();

    int wave = tid >> 6, lane = tid & 63;
    int m = lane & 15, q = lane >> 4;
    int n0 = blockIdx.x * 64 + wave * 16;

    f32x4 acc[4] = {{0.f,0.f,0.f,0.f},{0.f,0.f,0.f,0.f},{0.f,0.f,0.f,0.f},{0.f,0.f,0.f,0.f}};
    int row = n0 + m;
    int rowc = row < NN ? row : NN - 1;

    #pragma unroll
    for (int kk = 0; kk < K / 32; ++kk) {
        short8 afrag;
        if (BF16IN) {
            const unsigned short* xr = (const unsigned short*)in_ + (long)rowc * K;
            afrag = *(const short8*)(xr + kk * 32 + q * 8);
        } else {
            const float* xr = (const float*)in_ + (long)rowc * K;
            const float4* p = (const float4*)(xr + kk * 32 + q * 8);
            float4 v0 = p[0], v1 = p[1];
            float xv[8] = {v0.x, v0.y, v0.z, v0.w, v1.x, v1.y, v1.z, v1.w};
            #pragma unroll
            for (int i2 = 0; i2 < 8; ++i2) afrag[i2] = (short)f2bf(xv[i2]);
        }
        #pragma unroll
        for (int nt = 0; nt < 4; ++nt) {
            const short8* bp = (const short8*)&Wt[(nt * 16 + m) * KP + kk * 32 + q * 8];
            acc[nt] = __builtin_amdgcn_mfma_f32_16x16x32_bf16(afrag, *bp, acc[nt], 0, 0, 0);
        }
    }

    // D layout: col=lane&15, row=(lane>>4)*4+reg  [m89-verified]
    #pragma unroll
    for (int reg = 0; reg < 4; ++reg) {
        int node = n0 + q * 4 + reg;
        if (node < NN) {
            #pragma unroll
            for (int nt = 0; nt < 4; ++nt)
                hout[(long)node * 64 + nt * 16 + m] = f2bf(acc[nt][reg]);
        }
    }
}

// ---------- per-node aggregation: 8 lanes per node, uint4 (8-col) gathers ----
// wave walks 8 independent nodes concurrently; unroll-2 over edges.
template <bool OUT_BF16>
__global__ __launch_bounds__(256) void k_agg(const int* __restrict__ row_ptr,
                                             const int* __restrict__ esrc,
                                             const unsigned short* __restrict__ h,
                                             const float* __restrict__ dinv,
                                             const float* __restrict__ bias,
                                             const float* __restrict__ alpha,
                                             void* __restrict__ out_) {
    int sl = threadIdx.x & 7;          // column group: 8 bf16 columns
    int node = blockIdx.x * 32 + (threadIdx.x >> 3);
    if (node >= NN) return;
    int start = row_ptr[node], end = row_ptr[node + 1];
    float dn = dinv[node];

    float acc[8];
    {   // self-loop: norm = dn^2
        uint4 hw = *(const uint4*)(h + (long)node * 64 + sl * 8);
        float d2 = dn * dn;
        acc[0] = bf_lo(hw.x) * d2; acc[1] = bf_hi(hw.x) * d2;
        acc[2] = bf_lo(hw.y) * d2; acc[3] = bf_hi(hw.y) * d2;
        acc[4] = bf_lo(hw.z) * d2; acc[5] = bf_hi(hw.z) * d2;
        acc[6] = bf_lo(hw.w) * d2; acc[7] = bf_hi(hw.w) * d2;
    }

    int i = start;
    for (; i + 1 < end; i += 2) {
        int s0 = esrc[i], s1 = esrc[i + 1];
        float n0 = dinv[s0] * dn, n1 = dinv[s1] * dn;
        uint4 w0 = *(const uint4*)(h + (long)s0 * 64 + sl * 8);
        uint4 w1 = *(const uint4*)(h + (long)s1 * 64 + sl * 8);
        acc[0] += bf_lo(w0.x) * n0; acc[1] += bf_hi(w0.x) * n0;
        acc[2] += bf_lo(w0.y) * n0; acc[3] += bf_hi(w0.y) * n0;
        acc[4] += bf_lo(w0.z) * n0; acc[5] += bf_hi(w0.z) * n0;
        acc[6] += bf_lo(w0.w) * n0; acc[7] += bf_hi(w0.w) * n0;
        acc[0] += bf_lo(w1.x) * n1; acc[1] += bf_hi(w1.x) * n1;
        acc[2] += bf_lo(w1.y) * n1; acc[3] += bf_hi(w1.y) * n1;
        acc[4] += bf_lo(w1.z) * n1; acc[5] += bf_hi(w1.z) * n1;
        acc[6] += bf_lo(w1.w) * n1; acc[7] += bf_hi(w1.w) * n1;
    }
    if (i < end) {
        int s0 = esrc[i];
        float n0 = dinv[s0] * dn;
        uint4 w0 = *(const uint4*)(h + (long)s0 * 64 + sl * 8);
        acc[0] += bf_lo(w0.x) * n0; acc[1] += bf_hi(w0.x) * n0;
        acc[2] += bf_lo(w0.y) * n0; acc[3] += bf_hi(w0.y) * n0;
        acc[4] += bf_lo(w0.z) * n0; acc[5] += bf_hi(w0.z) * n0;
        acc[6] += bf_lo(w0.w) * n0; acc[7] += bf_hi(w0.w) * n0;
    }

    // epilogue: bias + PReLU on columns sl*8 .. sl*8+7
    float4 blo = *(const float4*)(bias + sl * 8);
    float4 bhi = *(const float4*)(bias + sl * 8 + 4);
    float4 alo = *(const float4*)(alpha + sl * 8);
    float4 ahi = *(const float4*)(alpha + sl * 8 + 4);
    float bb[8] = {blo.x, blo.y, blo.z, blo.w, bhi.x, bhi.y, bhi.z, bhi.w};
    float aa[8] = {alo.x, alo.y, alo.z, alo.w, ahi.x, ahi.y, ahi.z, ahi.w};
    #pragma unroll
    for (int j = 0; j < 8; ++j) {
        float v = acc[j] + bb[j];
        acc[j] = v >= 0.f ? v : aa[j] * v;
    }

    if (OUT_BF16) {
        uint4 pk;
        pk.x = (unsigned)f2bf(acc[0]) | ((unsigned)f2bf(acc[1]) << 16);
        pk.y = (unsigned)f2bf(acc[2]) | ((unsigned)f2bf(acc[3]) << 16);
        pk.z = (unsigned)f2bf(acc[4]) | ((unsigned)f2bf(acc[5]) << 16);
        pk.w = (unsigned)f2bf(acc[6]) | ((unsigned)f2bf(acc[7]) << 16);
        *(uint4*)((unsigned short*)out_ + (long)node * 64 + sl * 8) = pk;
    } else {
        float* op = (float*)out_ + (long)node * 64 + sl * 8;
        *(float4*)op = make_float4(acc[0], acc[1], acc[2], acc[3]);
        *(float4*)(op + 4) = make_float4(acc[4], acc[5], acc[6], acc[7]);
    }
}

extern "C" void kernel_launch(void* const* d_in, const int* in_sizes, int n_in,
                              void* d_out, int out_size, void* d_ws, size_t ws_size,
                              hipStream_t stream) {
    const float* x     = (const float*)d_in[0];
    const int*   ei    = (const int*)d_in[1];
    const float* W1    = (const float*)d_in[2];
    const float* b1    = (const float*)d_in[3];
    const float* W2    = (const float*)d_in[4];
    const float* b2    = (const float*)d_in[5];
    const float* alpha = (const float*)d_in[6];
    float* out = (float*)d_out;

    char* ws = (char*)d_ws;
    float* dinv          = (float*)(ws);                     //        0: 400,384
    int*   row_ptr       = (int*)(ws + 400384);              //   400384: 400,384
    int*   bcnt          = (int*)(ws + 800768);              //   800768: 512
    int*   bbase         = (int*)(ws + 801280);              //   801280: 512
    int*   bcur          = (int*)(ws + 801792);              //   801792: 512
    int*   esrc          = (int*)(ws + 802304);              //   802304: 6,400,000
    unsigned short* hbf  = (unsigned short*)(ws + 7202304);  //  7202304: 12,800,000
    unsigned* ebuf       = (unsigned*)(ws + 20002304);       // 20002304: 6,400,000 (dead after k_build)
    unsigned short* aggbf= (unsigned short*)(ws + 20002304); // alias ebuf: 12,800,000
    // total: 32,802,304 B

    hipMemsetAsync(bcnt, 0, NBUCK * sizeof(int), stream);
    k_bcount<<<256, 256, 0, stream>>>(ei, bcnt);
    k_bbase<<<1, 128, 0, stream>>>(bcnt, bbase, bcur);
    k_partition<<<(NE + CHUNK - 1) / CHUNK, 256, 0, stream>>>(ei, bcur, ebuf);
    k_build<<<NBUCK, 1024, 0, stream>>>(bbase, bcnt, ebuf, row_ptr, dinv, esrc);

    // layer 1: h1 = x@W1 (bf16) ; agg1 = prelu(scatter+self+b1) -> bf16
    k_mm<128, false><<<(NN + 63) / 64, 256, 0, stream>>>(x, W1, hbf);
    k_agg<true><<<(NN + 31) / 32, 256, 0, stream>>>(row_ptr, esrc, hbf, dinv, b1, alpha, aggbf);
    // layer 2: h2 = agg1@W2 (bf16 in) ; out = prelu(...) fp32
    k_mm<64, true><<<(NN + 63) / 64, 256, 0, stream>>>(aggbf, W2, hbf);
    k_agg<false><<<(NN + 31) / 32, 256, 0, stream>>>(row_ptr, esrc, hbf, dinv, b2, alpha, out);
}

// Round 7
// 241.406 us; speedup vs baseline: 1.2939x; 1.1052x over previous
//
#include <hip/hip_runtime.h>
#include <hip/hip_bf16.h>

#define NN 100000
#define NE 1600000
#define NBUCK 98   // ceil(NN / 1024)
#define CAP 20480  // per-bucket edge capacity (expected 16384, sigma~127)

typedef __attribute__((ext_vector_type(8))) short short8;
typedef __attribute__((ext_vector_type(4))) float f32x4;

static __device__ __forceinline__ unsigned short f2bf(float f) {
    unsigned u = __float_as_uint(f);
    unsigned r = (u + 0x7fffu + ((u >> 16) & 1u)) >> 16;
    return (unsigned short)r;
}
static __device__ __forceinline__ float bf_lo(unsigned u) {
    return __uint_as_float(u << 16);
}
static __device__ __forceinline__ float bf_hi(unsigned u) {
    return __uint_as_float(u & 0xffff0000u);
}
static __device__ __forceinline__ void acc8(float* acc, uint4 v, float nm) {
    acc[0] += bf_lo(v.x) * nm; acc[1] += bf_hi(v.x) * nm;
    acc[2] += bf_lo(v.y) * nm; acc[3] += bf_hi(v.y) * nm;
    acc[4] += bf_lo(v.z) * nm; acc[5] += bf_hi(v.z) * nm;
    acc[6] += bf_lo(v.w) * nm; acc[7] += bf_hi(v.w) * nm;
}

// ---------- bucketed CSR build (fixed-capacity buckets, no global scan) ------
#define CHUNK 8192
__global__ __launch_bounds__(256) void k_partition(const int* __restrict__ ei,
                                                   int* __restrict__ bcur,
                                                   unsigned* __restrict__ ebuf) {
    __shared__ int lh[NBUCK];
    __shared__ int lbase[NBUCK];
    int tid = threadIdx.x;
    int e0 = blockIdx.x * CHUNK;
    for (int i = tid; i < NBUCK; i += 256) lh[i] = 0;
    __syncthreads();
    #pragma unroll 4
    for (int k = 0; k < CHUNK; k += 256) {
        int e = e0 + k + tid;
        if (e < NE) atomicAdd(&lh[ei[NE + e] >> 10], 1);
    }
    __syncthreads();
    if (tid < NBUCK) {
        int c = lh[tid];
        lbase[tid] = c ? atomicAdd(&bcur[tid], c) : 0;  // within-bucket offset
        lh[tid] = 0;  // becomes local rank counter
    }
    __syncthreads();
    #pragma unroll 4
    for (int k = 0; k < CHUNK; k += 256) {
        int e = e0 + k + tid;
        if (e < NE) {
            int d = ei[NE + e];
            int s = ei[e];
            int b = d >> 10;
            int r = atomicAdd(&lh[b], 1);
            int pos = lbase[b] + r;
            if (pos < CAP)  // safety clamp; never hit for uniform input
                ebuf[(long)b * CAP + pos] = ((unsigned)s << 10) | (unsigned)(d & 1023);
        }
    }
}

// one block per bucket: per-node counts -> local scan -> rowinfo/dinv -> scatter
// rowinfo[node] = (start << 11) | degree   (start < 2^21, degree < 2^11)
__global__ __launch_bounds__(1024) void k_build(const int* __restrict__ bcur,
                                                const unsigned* __restrict__ ebuf,
                                                unsigned* __restrict__ rowinfo,
                                                float* __restrict__ dinv,
                                                int* __restrict__ esrc) {
    __shared__ int cnt[1024];
    __shared__ int s[1024];
    int tid = threadIdx.x;
    int base = blockIdx.x * CAP;
    int nedge = bcur[blockIdx.x];
    if (nedge > CAP) nedge = CAP;
    cnt[tid] = 0;
    __syncthreads();
    for (int j = tid; j < nedge; j += 1024)
        atomicAdd(&cnt[ebuf[base + j] & 1023u], 1);
    __syncthreads();
    int v = cnt[tid];
    s[tid] = v;
    __syncthreads();
    #pragma unroll
    for (int off = 1; off < 1024; off <<= 1) {
        int t = (tid >= off) ? s[tid - off] : 0;
        __syncthreads();
        s[tid] += t;
        __syncthreads();
    }
    int ex = s[tid] - v;
    int node = blockIdx.x * 1024 + tid;
    if (node < NN) {
        rowinfo[node] = ((unsigned)(base + ex) << 11) | (unsigned)v;
        dinv[node] = rsqrtf((float)(v + 1));  // +1 self-loop
    }
    cnt[tid] = base + ex;  // becomes cursor
    __syncthreads();
    for (int j = tid; j < nedge; j += 1024) {
        unsigned p = ebuf[base + j];
        int pos = atomicAdd(&cnt[p & 1023u], 1);
        esrc[pos] = (int)(p >> 10);
    }
}

// ---------- h = in @ W  [N x K] @ [K x 64] -> bf16; in fp32 or bf16 ----------
template <int K, bool BF16IN>
__global__ __launch_bounds__(256) void k_mm(const void* __restrict__ in_,
                                            const float* __restrict__ W,
                                            unsigned short* __restrict__ hout) {
    constexpr int KP = K + 8;  // 2-way bank alias only (free)
    __shared__ unsigned short Wt[64 * KP];
    int tid = threadIdx.x;
    for (int idx = tid; idx < K * 64; idx += 256) {
        int k = idx >> 6, n = idx & 63;
        Wt[n * KP + k] = f2bf(W[idx]);
    }
    __syncthreads();

    int wave = tid >> 6, lane = tid & 63;
    int m = lane & 15, q = lane >> 4;
    int n0 = blockIdx.x * 64 + wave * 16;

    f32x4 acc[4] = {{0.f,0.f,0.f,0.f},{0.f,0.f,0.f,0.f},{0.f,0.f,0.f,0.f},{0.f,0.f,0.f,0.f}};
    int row = n0 + m;
    int rowc = row < NN ? row : NN - 1;

    #pragma unroll
    for (int kk = 0; kk < K / 32; ++kk) {
        short8 afrag;
        if (BF16IN) {
            const unsigned short* xr = (const unsigned short*)in_ + (long)rowc * K;
            afrag = *(const short8*)(xr + kk * 32 + q * 8);
        } else {
            const float* xr = (const float*)in_ + (long)rowc * K;
            const float4* p = (const float4*)(xr + kk * 32 + q * 8);
            float4 v0 = p[0], v1 = p[1];
            float xv[8] = {v0.x, v0.y, v0.z, v0.w, v1.x, v1.y, v1.z, v1.w};
            #pragma unroll
            for (int i2 = 0; i2 < 8; ++i2) afrag[i2] = (short)f2bf(xv[i2]);
        }
        #pragma unroll
        for (int nt = 0; nt < 4; ++nt) {
            const short8* bp = (const short8*)&Wt[(nt * 16 + m) * KP + kk * 32 + q * 8];
            acc[nt] = __builtin_amdgcn_mfma_f32_16x16x32_bf16(afrag, *bp, acc[nt], 0, 0, 0);
        }
    }

    // D layout: col=lane&15, row=(lane>>4)*4+reg  [m89-verified]
    #pragma unroll
    for (int reg = 0; reg < 4; ++reg) {
        int node = n0 + q * 4 + reg;
        if (node < NN) {
            #pragma unroll
            for (int nt = 0; nt < 4; ++nt)
                hout[(long)node * 64 + nt * 16 + m] = f2bf(acc[nt][reg]);
        }
    }
}

// ---------- per-node aggregation: 8 lanes/node, uint4 gathers, unroll-4 ------
template <bool OUT_BF16>
__global__ __launch_bounds__(256) void k_agg(const unsigned* __restrict__ rowinfo,
                                             const int* __restrict__ esrc,
                                             const unsigned short* __restrict__ h,
                                             const float* __restrict__ dinv,
                                             const float* __restrict__ bias,
                                             const float* __restrict__ alpha,
                                             void* __restrict__ out_) {
    int sl = threadIdx.x & 7;          // 8 bf16 columns per lane
    int node = blockIdx.x * 32 + (threadIdx.x >> 3);
    if (node >= NN) return;
    unsigned u = rowinfo[node];
    int start = (int)(u >> 11);
    int cnt = (int)(u & 2047u);
    float dn = dinv[node];
    const unsigned short* hc = h + sl * 8;

    float acc[8];
    {   // self-loop: norm = dn^2
        uint4 hw = *(const uint4*)(hc + (long)node * 64);
        float d2 = dn * dn;
        acc[0] = bf_lo(hw.x) * d2; acc[1] = bf_hi(hw.x) * d2;
        acc[2] = bf_lo(hw.y) * d2; acc[3] = bf_hi(hw.y) * d2;
        acc[4] = bf_lo(hw.z) * d2; acc[5] = bf_hi(hw.z) * d2;
        acc[6] = bf_lo(hw.w) * d2; acc[7] = bf_hi(hw.w) * d2;
    }

    int i = 0;
    for (; i + 4 <= cnt; i += 4) {
        int s0 = esrc[start + i];
        int s1 = esrc[start + i + 1];
        int s2 = esrc[start + i + 2];
        int s3 = esrc[start + i + 3];
        float n0 = dinv[s0] * dn, n1 = dinv[s1] * dn;
        float n2 = dinv[s2] * dn, n3 = dinv[s3] * dn;
        uint4 w0 = *(const uint4*)(hc + (long)s0 * 64);
        uint4 w1 = *(const uint4*)(hc + (long)s1 * 64);
        uint4 w2 = *(const uint4*)(hc + (long)s2 * 64);
        uint4 w3 = *(const uint4*)(hc + (long)s3 * 64);
        acc8(acc, w0, n0); acc8(acc, w1, n1); acc8(acc, w2, n2); acc8(acc, w3, n3);
    }
    for (; i < cnt; ++i) {
        int s0 = esrc[start + i];
        float n0 = dinv[s0] * dn;
        uint4 w0 = *(const uint4*)(hc + (long)s0 * 64);
        acc8(acc, w0, n0);
    }

    // epilogue: bias + PReLU on columns sl*8 .. sl*8+7
    float4 blo = *(const float4*)(bias + sl * 8);
    float4 bhi = *(const float4*)(bias + sl * 8 + 4);
    float4 alo = *(const float4*)(alpha + sl * 8);
    float4 ahi = *(const float4*)(alpha + sl * 8 + 4);
    float bb[8] = {blo.x, blo.y, blo.z, blo.w, bhi.x, bhi.y, bhi.z, bhi.w};
    float aa[8] = {alo.x, alo.y, alo.z, alo.w, ahi.x, ahi.y, ahi.z, ahi.w};
    #pragma unroll
    for (int j = 0; j < 8; ++j) {
        float v = acc[j] + bb[j];
        acc[j] = v >= 0.f ? v : aa[j] * v;
    }

    if (OUT_BF16) {
        uint4 pk;
        pk.x = (unsigned)f2bf(acc[0]) | ((unsigned)f2bf(acc[1]) << 16);
        pk.y = (unsigned)f2bf(acc[2]) | ((unsigned)f2bf(acc[3]) << 16);
        pk.z = (unsigned)f2bf(acc[4]) | ((unsigned)f2bf(acc[5]) << 16);
        pk.w = (unsigned)f2bf(acc[6]) | ((unsigned)f2bf(acc[7]) << 16);
        *(uint4*)((unsigned short*)out_ + (long)node * 64 + sl * 8) = pk;
    } else {
        float* op = (float*)out_ + (long)node * 64 + sl * 8;
        *(float4*)op = make_float4(acc[0], acc[1], acc[2], acc[3]);
        *(float4*)(op + 4) = make_float4(acc[4], acc[5], acc[6], acc[7]);
    }
}

extern "C" void kernel_launch(void* const* d_in, const int* in_sizes, int n_in,
                              void* d_out, int out_size, void* d_ws, size_t ws_size,
                              hipStream_t stream) {
    const float* x     = (const float*)d_in[0];
    const int*   ei    = (const int*)d_in[1];
    const float* W1    = (const float*)d_in[2];
    const float* b1    = (const float*)d_in[3];
    const float* W2    = (const float*)d_in[4];
    const float* b2    = (const float*)d_in[5];
    const float* alpha = (const float*)d_in[6];
    float* out = (float*)d_out;

    char* ws = (char*)d_ws;
    float*    dinv      = (float*)(ws);                      //        0: 400,384
    unsigned* rowinfo   = (unsigned*)(ws + 400384);          //   400384: 400,384
    int*      bcur      = (int*)(ws + 800768);               //   800768: 512
    int*      esrc      = (int*)(ws + 801280);               //   801280: 8,028,160 (98*CAP ints)
    unsigned short* hbf = (unsigned short*)(ws + 8829440);   //  8829440: 12,800,000
    unsigned* ebuf      = (unsigned*)(ws + 21629440);        // 21629440: 8,028,160 (dead after k_build)
    unsigned short* aggbf = (unsigned short*)(ws + 21629440);// alias ebuf: 12,800,000
    // total: 34,429,440 B

    (void)hipMemsetAsync(bcur, 0, NBUCK * sizeof(int), stream);
    k_partition<<<(NE + CHUNK - 1) / CHUNK, 256, 0, stream>>>(ei, bcur, ebuf);
    k_build<<<NBUCK, 1024, 0, stream>>>(bcur, ebuf, rowinfo, dinv, esrc);

    // layer 1: h1 = x@W1 (bf16) ; agg1 = prelu(scatter+self+b1) -> bf16
    k_mm<128, false><<<(NN + 63) / 64, 256, 0, stream>>>(x, W1, hbf);
    k_agg<true><<<(NN + 31) / 32, 256, 0, stream>>>(rowinfo, esrc, hbf, dinv, b1, alpha, aggbf);
    // layer 2: h2 = agg1@W2 (bf16 in) ; out = prelu(...) fp32
    k_mm<64, true><<<(NN + 63) / 64, 256, 0, stream>>>(aggbf, W2, hbf);
    k_agg<false><<<(NN + 31) / 32, 256, 0, stream>>>(rowinfo, esrc, hbf, dinv, b2, alpha, out);
}

// Round 8
// 238.639 us; speedup vs baseline: 1.3089x; 1.0116x over previous
//
#include <hip/hip_runtime.h>
#include <hip/hip_bf16.h>

#define NN 100000
#define NE 1600000
#define NBUCK 391  // ceil(NN / 256)
#define CAP 5120   // per-bucket edge capacity (expected 4096, sigma~64)

typedef __attribute__((ext_vector_type(8))) short short8;
typedef __attribute__((ext_vector_type(4))) float f32x4;

static __device__ __forceinline__ unsigned short f2bf(float f) {
    unsigned u = __float_as_uint(f);
    unsigned r = (u + 0x7fffu + ((u >> 16) & 1u)) >> 16;
    return (unsigned short)r;
}
static __device__ __forceinline__ float bf_lo(unsigned u) {
    return __uint_as_float(u << 16);
}
static __device__ __forceinline__ float bf_hi(unsigned u) {
    return __uint_as_float(u & 0xffff0000u);
}
static __device__ __forceinline__ void acc8(float* acc, uint4 v, float nm) {
    acc[0] += bf_lo(v.x) * nm; acc[1] += bf_hi(v.x) * nm;
    acc[2] += bf_lo(v.y) * nm; acc[3] += bf_hi(v.y) * nm;
    acc[4] += bf_lo(v.z) * nm; acc[5] += bf_hi(v.z) * nm;
    acc[6] += bf_lo(v.w) * nm; acc[7] += bf_hi(v.w) * nm;
}

// ---------- bucketed CSR build (fixed-capacity buckets, no global scan) ------
// bucket = dst >> 8 (256 nodes per bucket); pack = (src<<8)|(dst&255)
#define CHUNK 2048
__global__ __launch_bounds__(256) void k_partition(const int* __restrict__ ei,
                                                   int* __restrict__ bcur,
                                                   unsigned* __restrict__ ebuf) {
    __shared__ int lh[NBUCK];
    __shared__ int lbase[NBUCK];
    int tid = threadIdx.x;
    int e0 = blockIdx.x * CHUNK;
    for (int i = tid; i < NBUCK; i += 256) lh[i] = 0;
    __syncthreads();
    #pragma unroll
    for (int k = 0; k < CHUNK; k += 256) {
        int e = e0 + k + tid;
        if (e < NE) atomicAdd(&lh[ei[NE + e] >> 8], 1);
    }
    __syncthreads();
    for (int i = tid; i < NBUCK; i += 256) {
        int c = lh[i];
        lbase[i] = c ? atomicAdd(&bcur[i], c) : 0;  // within-bucket offset
        lh[i] = 0;  // becomes local rank counter
    }
    __syncthreads();
    #pragma unroll
    for (int k = 0; k < CHUNK; k += 256) {
        int e = e0 + k + tid;
        if (e < NE) {
            int d = ei[NE + e];
            int s = ei[e];
            int b = d >> 8;
            int r = atomicAdd(&lh[b], 1);
            int pos = lbase[b] + r;
            if (pos < CAP)  // safety clamp; never hit for uniform input
                ebuf[(long)b * CAP + pos] = ((unsigned)s << 8) | (unsigned)(d & 255);
        }
    }
}

// one block (256 thr) per bucket: count -> shfl-scan -> rowinfo/dinv -> scatter
// rowinfo[node] = (start << 11) | degree   (start < 391*5120 < 2^21, deg < 2^11)
__global__ __launch_bounds__(256) void k_build(const int* __restrict__ bcur,
                                               const unsigned* __restrict__ ebuf,
                                               unsigned* __restrict__ rowinfo,
                                               float* __restrict__ dinv,
                                               int* __restrict__ esrc) {
    __shared__ int cnt[256];
    __shared__ int wsum[4];
    int tid = threadIdx.x;
    int base = blockIdx.x * CAP;
    int nedge = bcur[blockIdx.x];
    if (nedge > CAP) nedge = CAP;
    cnt[tid] = 0;
    __syncthreads();
    for (int j = tid; j < nedge; j += 256)
        atomicAdd(&cnt[ebuf[base + j] & 255u], 1);
    __syncthreads();
    int v = cnt[tid];
    // inclusive wave scan (64 lanes, no barriers)
    int lane = tid & 63;
    int incl = v;
    #pragma unroll
    for (int off = 1; off < 64; off <<= 1) {
        int t = __shfl_up(incl, off, 64);
        if (lane >= off) incl += t;
    }
    if (lane == 63) wsum[tid >> 6] = incl;
    __syncthreads();
    if (tid == 0) {
        int a = 0;
        #pragma unroll
        for (int w = 0; w < 4; ++w) { int t = wsum[w]; wsum[w] = a; a += t; }
    }
    __syncthreads();
    int ex = incl - v + wsum[tid >> 6];
    int node = blockIdx.x * 256 + tid;
    if (node < NN) {
        rowinfo[node] = ((unsigned)(base + ex) << 11) | (unsigned)v;
        dinv[node] = rsqrtf((float)(v + 1));  // +1 self-loop
    }
    cnt[tid] = base + ex;  // becomes cursor
    __syncthreads();
    for (int j = tid; j < nedge; j += 256) {
        unsigned p = ebuf[base + j];
        int pos = atomicAdd(&cnt[p & 255u], 1);
        esrc[pos] = (int)(p >> 8);
    }
}

// ---------- h = in @ W  [N x K] @ [K x 64] -> bf16; in fp32 or bf16 ----------
template <int K, bool BF16IN>
__global__ __launch_bounds__(256) void k_mm(const void* __restrict__ in_,
                                            const float* __restrict__ W,
                                            unsigned short* __restrict__ hout) {
    constexpr int KP = K + 8;  // 2-way bank alias only (free)
    __shared__ unsigned short Wt[64 * KP];
    int tid = threadIdx.x;
    for (int idx = tid; idx < K * 64; idx += 256) {
        int k = idx >> 6, n = idx & 63;
        Wt[n * KP + k] = f2bf(W[idx]);
    }
    __syncthreads();

    int wave = tid >> 6, lane = tid & 63;
    int m = lane & 15, q = lane >> 4;
    int n0 = blockIdx.x * 64 + wave * 16;

    f32x4 acc[4] = {{0.f,0.f,0.f,0.f},{0.f,0.f,0.f,0.f},{0.f,0.f,0.f,0.f},{0.f,0.f,0.f,0.f}};
    int row = n0 + m;
    int rowc = row < NN ? row : NN - 1;

    #pragma unroll
    for (int kk = 0; kk < K / 32; ++kk) {
        short8 afrag;
        if (BF16IN) {
            const unsigned short* xr = (const unsigned short*)in_ + (long)rowc * K;
            afrag = *(const short8*)(xr + kk * 32 + q * 8);
        } else {
            const float* xr = (const float*)in_ + (long)rowc * K;
            const float4* p = (const float4*)(xr + kk * 32 + q * 8);
            float4 v0 = p[0], v1 = p[1];
            float xv[8] = {v0.x, v0.y, v0.z, v0.w, v1.x, v1.y, v1.z, v1.w};
            #pragma unroll
            for (int i2 = 0; i2 < 8; ++i2) afrag[i2] = (short)f2bf(xv[i2]);
        }
        #pragma unroll
        for (int nt = 0; nt < 4; ++nt) {
            const short8* bp = (const short8*)&Wt[(nt * 16 + m) * KP + kk * 32 + q * 8];
            acc[nt] = __builtin_amdgcn_mfma_f32_16x16x32_bf16(afrag, *bp, acc[nt], 0, 0, 0);
        }
    }

    // D layout: col=lane&15, row=(lane>>4)*4+reg  [m89-verified]
    #pragma unroll
    for (int reg = 0; reg < 4; ++reg) {
        int node = n0 + q * 4 + reg;
        if (node < NN) {
            #pragma unroll
            for (int nt = 0; nt < 4; ++nt)
                hout[(long)node * 64 + nt * 16 + m] = f2bf(acc[nt][reg]);
        }
    }
}

// ---------- per-node aggregation: 8 lanes/node, uint4 gathers, unroll-4 ------
template <bool OUT_BF16>
__global__ __launch_bounds__(256) void k_agg(const unsigned* __restrict__ rowinfo,
                                             const int* __restrict__ esrc,
                                             const unsigned short* __restrict__ h,
                                             const float* __restrict__ dinv,
                                             const float* __restrict__ bias,
                                             const float* __restrict__ alpha,
                                             void* __restrict__ out_) {
    int sl = threadIdx.x & 7;          // 8 bf16 columns per lane
    int node = blockIdx.x * 32 + (threadIdx.x >> 3);
    if (node >= NN) return;
    unsigned u = rowinfo[node];
    int start = (int)(u >> 11);
    int cnt = (int)(u & 2047u);
    float dn = dinv[node];
    const unsigned short* hc = h + sl * 8;

    float acc[8];
    {   // self-loop: norm = dn^2
        uint4 hw = *(const uint4*)(hc + (long)node * 64);
        float d2 = dn * dn;
        acc[0] = bf_lo(hw.x) * d2; acc[1] = bf_hi(hw.x) * d2;
        acc[2] = bf_lo(hw.y) * d2; acc[3] = bf_hi(hw.y) * d2;
        acc[4] = bf_lo(hw.z) * d2; acc[5] = bf_hi(hw.z) * d2;
        acc[6] = bf_lo(hw.w) * d2; acc[7] = bf_hi(hw.w) * d2;
    }

    int i = 0;
    for (; i + 4 <= cnt; i += 4) {
        int s0 = esrc[start + i];
        int s1 = esrc[start + i + 1];
        int s2 = esrc[start + i + 2];
        int s3 = esrc[start + i + 3];
        float n0 = dinv[s0] * dn, n1 = dinv[s1] * dn;
        float n2 = dinv[s2] * dn, n3 = dinv[s3] * dn;
        uint4 w0 = *(const uint4*)(hc + (long)s0 * 64);
        uint4 w1 = *(const uint4*)(hc + (long)s1 * 64);
        uint4 w2 = *(const uint4*)(hc + (long)s2 * 64);
        uint4 w3 = *(const uint4*)(hc + (long)s3 * 64);
        acc8(acc, w0, n0); acc8(acc, w1, n1); acc8(acc, w2, n2); acc8(acc, w3, n3);
    }
    for (; i < cnt; ++i) {
        int s0 = esrc[start + i];
        float n0 = dinv[s0] * dn;
        uint4 w0 = *(const uint4*)(hc + (long)s0 * 64);
        acc8(acc, w0, n0);
    }

    // epilogue: bias + PReLU on columns sl*8 .. sl*8+7
    float4 blo = *(const float4*)(bias + sl * 8);
    float4 bhi = *(const float4*)(bias + sl * 8 + 4);
    float4 alo = *(const float4*)(alpha + sl * 8);
    float4 ahi = *(const float4*)(alpha + sl * 8 + 4);
    float bb[8] = {blo.x, blo.y, blo.z, blo.w, bhi.x, bhi.y, bhi.z, bhi.w};
    float aa[8] = {alo.x, alo.y, alo.z, alo.w, ahi.x, ahi.y, ahi.z, ahi.w};
    #pragma unroll
    for (int j = 0; j < 8; ++j) {
        float v = acc[j] + bb[j];
        acc[j] = v >= 0.f ? v : aa[j] * v;
    }

    if (OUT_BF16) {
        uint4 pk;
        pk.x = (unsigned)f2bf(acc[0]) | ((unsigned)f2bf(acc[1]) << 16);
        pk.y = (unsigned)f2bf(acc[2]) | ((unsigned)f2bf(acc[3]) << 16);
        pk.z = (unsigned)f2bf(acc[4]) | ((unsigned)f2bf(acc[5]) << 16);
        pk.w = (unsigned)f2bf(acc[6]) | ((unsigned)f2bf(acc[7]) << 16);
        *(uint4*)((unsigned short*)out_ + (long)node * 64 + sl * 8) = pk;
    } else {
        float* op = (float*)out_ + (long)node * 64 + sl * 8;
        *(float4*)op = make_float4(acc[0], acc[1], acc[2], acc[3]);
        *(float4*)(op + 4) = make_float4(acc[4], acc[5], acc[6], acc[7]);
    }
}

extern "C" void kernel_launch(void* const* d_in, const int* in_sizes, int n_in,
                              void* d_out, int out_size, void* d_ws, size_t ws_size,
                              hipStream_t stream) {
    const float* x     = (const float*)d_in[0];
    const int*   ei    = (const int*)d_in[1];
    const float* W1    = (const float*)d_in[2];
    const float* b1    = (const float*)d_in[3];
    const float* W2    = (const float*)d_in[4];
    const float* b2    = (const float*)d_in[5];
    const float* alpha = (const float*)d_in[6];
    float* out = (float*)d_out;

    char* ws = (char*)d_ws;
    float*    dinv      = (float*)(ws);                      //        0: 400,384
    unsigned* rowinfo   = (unsigned*)(ws + 400384);          //   400384: 400,384
    int*      bcur      = (int*)(ws + 800768);               //   800768: 2,048
    int*      esrc      = (int*)(ws + 802816);               //   802816: 8,007,680 (391*CAP)
    unsigned short* hbf = (unsigned short*)(ws + 8810496);   //  8810496: 12,800,000
    unsigned* ebuf      = (unsigned*)(ws + 21610496);        // 21610496: 8,007,680 (dead after k_build)
    unsigned short* aggbf = (unsigned short*)(ws + 21610496);// alias ebuf: 12,800,000
    // total: 34,410,496 B

    (void)hipMemsetAsync(bcur, 0, NBUCK * sizeof(int), stream);
    k_partition<<<(NE + CHUNK - 1) / CHUNK, 256, 0, stream>>>(ei, bcur, ebuf);
    k_build<<<NBUCK, 256, 0, stream>>>(bcur, ebuf, rowinfo, dinv, esrc);

    // layer 1: h1 = x@W1 (bf16) ; agg1 = prelu(scatter+self+b1) -> bf16
    k_mm<128, false><<<(NN + 63) / 64, 256, 0, stream>>>(x, W1, hbf);
    k_agg<true><<<(NN + 31) / 32, 256, 0, stream>>>(rowinfo, esrc, hbf, dinv, b1, alpha, aggbf);
    // layer 2: h2 = agg1@W2 (bf16 in) ; out = prelu(...) fp32
    k_mm<64, true><<<(NN + 63) / 64, 256, 0, stream>>>(aggbf, W2, hbf);
    k_agg<false><<<(NN + 31) / 32, 256, 0, stream>>>(rowinfo, esrc, hbf, dinv, b2, alpha, out);
}